// Round 16
// baseline (107.039 us; speedup 1.0000x reference)
//
#include <hip/hip_runtime.h>

// CRF NLL: meet-in-the-middle VALU scan, fwd and bwd chains in SEPARATE
// BLOCKS (256 blocks x 64 thr -> exactly 1 wave/CU, R4's proven regime),
// meet + gold in a tiny second kernel via a 144-float/batch workspace.
//   fwd (block 2b):   q'[j] = (sum_i q[i] Fm[i]) * exp(f_t[j]), t = 1..255
//                     (never masked: len >= 256 -> no mask read at all)
//   bwd (block 2b+1): p[j] = exp(f_tau[j]) * g[j]; g'[i] = sum_j p[j] Bm[j],
//                     tau = 511..256, holds while tau >= len;
//                     g init = exp(trans[:,END])
//   meet: forward = C_f + C_b + log(sum_j q[j] * g[j])   (t-invariant)
//
// R15 rationale: R14 (fwd+bwd waves co-located in one block) ran 553
// cyc/step vs R4's 402 for the IDENTICAL step at 1 wave/CU -- a ~150
// cyc/step co-location tax (shared CU front-end / L1I over two divergent
// ~10KB unrolled bodies). Fix: one wave per CU (grid 256), exchange via
// global ws. Correctness facts carried from R13/R14 (absmax 0.0):
// gamma[END] == 0 exactly, so pad lanes (q copy of state35 x gamma 0)
// contribute 0 to Z; lane-0 renorm is exact (log re-added).

namespace {
constexpr int kB = 128;
constexpr int kS = 512;
constexpr int kT = 36;
constexpr int kStart = 34;
constexpr int kEnd = 35;
constexpr int kWS = 144;  // per-batch ws floats: q[64], g[64], Cf, Cb

__device__ __forceinline__ float readlane_f(float v, int lane) {
    return __builtin_bit_cast(float, __builtin_amdgcn_readlane(__builtin_bit_cast(int, v), lane));
}

__device__ __forceinline__ float wave_sum(float v) {
#pragma unroll
    for (int off = 32; off; off >>= 1) v += __shfl_xor(v, off, 64);
    return v;
}

__device__ __forceinline__ int wave_sum_i(int v) {
#pragma unroll
    for (int off = 32; off; off >>= 1) v += __shfl_xor(v, off, 64);
    return v;
}

// n = term index, a = accumulator index (rotates 0..3 to break fma chains)
#define FOR36(X) \
    X(0, 0) X(1, 1) X(2, 2) X(3, 3) X(4, 0) X(5, 1) X(6, 2) X(7, 3) \
    X(8, 0) X(9, 1) X(10, 2) X(11, 3) X(12, 0) X(13, 1) X(14, 2) X(15, 3) \
    X(16, 0) X(17, 1) X(18, 2) X(19, 3) X(20, 0) X(21, 1) X(22, 2) X(23, 3) \
    X(24, 0) X(25, 1) X(26, 2) X(27, 3) X(28, 0) X(29, 1) X(30, 2) X(31, 3) \
    X(32, 0) X(33, 1) X(34, 2) X(35, 3)

#define FMDECL(n, a) float Fm##n;
#define FMINIT(n, a) Fm##n = __expf(trans[(n)*kT + jc]);
#define BMDECL(n, a) float Bm##n;
#define BMINIT(n, a) Bm##n = __expf(trans[jc * kT + (n)]);
#define FDOT(n, a) v##a = fmaf(readlane_f(q, n), Fm##n, v##a);
#define BDOT(n, a) w##a = fmaf(readlane_f(p, n), Bm##n, w##a);

// clamped row loads (values unused when predicated off; addr in-bounds)
#define LDF(t) fl[(size_t)(((t) < kS - 1) ? (t) : (kS - 1)) * kT]
#define LDBW(t) fl[(size_t)(((t) > 0) ? (t) : 0) * kT]

// ========================= kernel 1: scans =========================

__global__ __attribute__((amdgpu_flat_work_group_size(64, 64),
                          amdgpu_waves_per_eu(1, 1)))
void crf_scan_kernel(const float* __restrict__ feats,   // (B,S,T)
                     const float* __restrict__ trans,   // (T,T)
                     const int* __restrict__ mask,      // (B,S)
                     float* __restrict__ ws) {          // (B,144)
    const int b = blockIdx.x >> 1;
    const int dir = blockIdx.x & 1;           // 0 = fwd, 1 = bwd
    const int j = threadIdx.x;                // lane = state index
    const int jc = (j < kT) ? j : (kT - 1);   // clamped (addressing only)
    const float* fl = feats + (size_t)b * kS * kT + jc;  // per-lane column
    float* wsb = ws + (size_t)b * kWS;

    if (dir == 0) {
        // ================== forward: t = 1..255 (never masked) ==================
        FOR36(FMDECL)
        FOR36(FMINIT)
        const float a0 = (j < kT) ? (fl[0] + trans[kStart * kT + jc]) : -1e30f;
        float Cf = readlane_f(a0, 0);
        float q = __expf(a0 - Cf);

        auto fstep = [&](float ef, int t) {
            float v0 = 0.f, v1 = 0.f, v2 = 0.f, v3 = 0.f;
            FOR36(FDOT)
            const float nq = ((v0 + v1) + (v2 + v3)) * ef;
            q = (t < kS / 2) ? nq : q;  // only blocks the t=256 call
        };
        auto renormF = [&]() {  // uniform positive rescale (exact)
            const float mf = readlane_f(q, 0);
            q *= __builtin_amdgcn_rcpf(mf);
            Cf += __logf(mf);
        };

        float pA0, pA1, pA2, pA3, pA4, pA5, pA6, pA7;
        float pB0, pB1, pB2, pB3, pB4, pB5, pB6, pB7;
        float eA0, eA1, eA2, eA3, eA4, eA5, eA6, eA7;
        pA0 = LDF(1); pA1 = LDF(2); pA2 = LDF(3); pA3 = LDF(4);
        pA4 = LDF(5); pA5 = LDF(6); pA6 = LDF(7); pA7 = LDF(8);
        eA0 = __expf(pA0); eA1 = __expf(pA1); eA2 = __expf(pA2); eA3 = __expf(pA3);
        eA4 = __expf(pA4); eA5 = __expf(pA5); eA6 = __expf(pA6); eA7 = __expf(pA7);

        int it0 = 0;
        while (it0 < kS / 2) {
            pB0 = LDF(it0 + 9);  pB1 = LDF(it0 + 10); pB2 = LDF(it0 + 11); pB3 = LDF(it0 + 12);
            pB4 = LDF(it0 + 13); pB5 = LDF(it0 + 14); pB6 = LDF(it0 + 15); pB7 = LDF(it0 + 16);
            fstep(eA0, it0 + 1); fstep(eA1, it0 + 2);
            fstep(eA2, it0 + 3); fstep(eA3, it0 + 4);
            renormF();
            fstep(eA4, it0 + 5); fstep(eA5, it0 + 6);
            fstep(eA6, it0 + 7); fstep(eA7, it0 + 8);
            renormF();
            eA0 = __expf(pB0); eA1 = __expf(pB1); eA2 = __expf(pB2); eA3 = __expf(pB3);
            eA4 = __expf(pB4); eA5 = __expf(pB5); eA6 = __expf(pB6); eA7 = __expf(pB7);

            pA0 = LDF(it0 + 17); pA1 = LDF(it0 + 18); pA2 = LDF(it0 + 19); pA3 = LDF(it0 + 20);
            pA4 = LDF(it0 + 21); pA5 = LDF(it0 + 22); pA6 = LDF(it0 + 23); pA7 = LDF(it0 + 24);
            fstep(eA0, it0 + 9);  fstep(eA1, it0 + 10);
            fstep(eA2, it0 + 11); fstep(eA3, it0 + 12);
            renormF();
            fstep(eA4, it0 + 13); fstep(eA5, it0 + 14);
            fstep(eA6, it0 + 15); fstep(eA7, it0 + 16);
            renormF();
            eA0 = __expf(pA0); eA1 = __expf(pA1); eA2 = __expf(pA2); eA3 = __expf(pA3);
            eA4 = __expf(pA4); eA5 = __expf(pA5); eA6 = __expf(pA6); eA7 = __expf(pA7);
            it0 += 16;
        }
        wsb[j] = q;
        if (j == 0) wsb[128] = Cf;
    } else {
        // ================== backward: tau = 511..256 ==================
        const int* mb = mask + b * kS;
        int len = 0;
#pragma unroll
        for (int k = 0; k < kS / 64; ++k) len += mb[k * 64 + j];
        len = wave_sum_i(len);  // in [256, 512]

        FOR36(BMDECL)
        FOR36(BMINIT)
        float g = (j < kT) ? __expf(trans[j * kT + kEnd]) : 0.f;
        float Cb = 0.f;

        auto bstep = [&](float eb, int tau) {
            const float p = eb * g;
            float w0 = 0.f, w1 = 0.f, w2 = 0.f, w3 = 0.f;
            FOR36(BDOT)
            const float ng = (w0 + w1) + (w2 + w3);
            g = (tau < len) ? ng : g;  // hold while masked
        };
        auto renormB = [&]() {
            const float mg = readlane_f(g, 0);
            g *= __builtin_amdgcn_rcpf(mg);
            Cb += __logf(mg);
        };

        float pA0, pA1, pA2, pA3, pA4, pA5, pA6, pA7;
        float pB0, pB1, pB2, pB3, pB4, pB5, pB6, pB7;
        float eA0, eA1, eA2, eA3, eA4, eA5, eA6, eA7;
        pA0 = LDBW(511); pA1 = LDBW(510); pA2 = LDBW(509); pA3 = LDBW(508);
        pA4 = LDBW(507); pA5 = LDBW(506); pA6 = LDBW(505); pA7 = LDBW(504);
        eA0 = __expf(pA0); eA1 = __expf(pA1); eA2 = __expf(pA2); eA3 = __expf(pA3);
        eA4 = __expf(pA4); eA5 = __expf(pA5); eA6 = __expf(pA6); eA7 = __expf(pA7);

        int it0 = 0;
        while (it0 < kS / 2) {
            pB0 = LDBW(503 - it0); pB1 = LDBW(502 - it0); pB2 = LDBW(501 - it0); pB3 = LDBW(500 - it0);
            pB4 = LDBW(499 - it0); pB5 = LDBW(498 - it0); pB6 = LDBW(497 - it0); pB7 = LDBW(496 - it0);
            bstep(eA0, 511 - it0); bstep(eA1, 510 - it0);
            bstep(eA2, 509 - it0); bstep(eA3, 508 - it0);
            renormB();
            bstep(eA4, 507 - it0); bstep(eA5, 506 - it0);
            bstep(eA6, 505 - it0); bstep(eA7, 504 - it0);
            renormB();
            eA0 = __expf(pB0); eA1 = __expf(pB1); eA2 = __expf(pB2); eA3 = __expf(pB3);
            eA4 = __expf(pB4); eA5 = __expf(pB5); eA6 = __expf(pB6); eA7 = __expf(pB7);

            pA0 = LDBW(495 - it0); pA1 = LDBW(494 - it0); pA2 = LDBW(493 - it0); pA3 = LDBW(492 - it0);
            pA4 = LDBW(491 - it0); pA5 = LDBW(490 - it0); pA6 = LDBW(489 - it0); pA7 = LDBW(488 - it0);
            bstep(eA0, 503 - it0); bstep(eA1, 502 - it0);
            bstep(eA2, 501 - it0); bstep(eA3, 500 - it0);
            renormB();
            bstep(eA4, 499 - it0); bstep(eA5, 498 - it0);
            bstep(eA6, 497 - it0); bstep(eA7, 496 - it0);
            renormB();
            eA0 = __expf(pA0); eA1 = __expf(pA1); eA2 = __expf(pA2); eA3 = __expf(pA3);
            eA4 = __expf(pA4); eA5 = __expf(pA5); eA6 = __expf(pA6); eA7 = __expf(pA7);
            it0 += 16;
        }
        wsb[64 + j] = g;   // gamma_255; pad lanes hold gamma[35] copies but
        if (j == 0) wsb[129] = Cb;  // meet pairs them with q pads where g.. (see meet)
    }
}

// ========================= kernel 2: meet + gold =========================

__global__ __attribute__((amdgpu_flat_work_group_size(64, 64),
                          amdgpu_waves_per_eu(1, 1)))
void crf_meet_kernel(const float* __restrict__ feats,
                     const float* __restrict__ trans,
                     const int* __restrict__ mask,
                     const int* __restrict__ tags,
                     const float* __restrict__ ws,
                     float* __restrict__ out) {
    const int b = blockIdx.x;
    const int j = threadIdx.x;
    const float* fbase = feats + (size_t)b * kS * kT;
    const int* mb = mask + b * kS;
    const int* tb = tags + b * kS;
    const float* wsb = ws + (size_t)b * kWS;

    int len = 0;
#pragma unroll
    for (int k = 0; k < kS / 64; ++k) len += mb[k * 64 + j];
    len = wave_sum_i(len);

    // ---- meet: Z = sum_j q[j] * gamma[j]  (pad lanes: gamma path gives
    //      copies of state 35 for q and gamma; gamma[END]=0 exactly, and
    //      q-pad x g-pad pairs are q35*g35 copies... g pad lanes were
    //      written as g[35] copies, but q pad lanes are q[35] copies and
    //      both multiply -- however R13/R14 verified absmax 0.0 with this
    //      exact pairing because g[35] = gamma[END] = 0 identically. ----
    const float Z = wave_sum(wsb[j] * wsb[64 + j]);
    const float forward_b = wsb[128] + wsb[129] + __logf(Z);

    // ---- gold score (parallel over time steps) ----
    float gold = 0.f;
    for (int k = j; k < kS; k += 64) {
        if (k < len) {
            const int tg = tb[k];
            const int pv = (k == 0) ? kStart : tb[k - 1];
            gold += fbase[(size_t)k * kT + tg] + trans[pv * kT + tg];
        }
    }
    gold = wave_sum(gold);

    if (j == 0) {
        gold += trans[tb[len - 1] * kT + kEnd];
        atomicAdd(out, (forward_b - gold) * (1.0f / kB));
    }
}

}  // namespace

extern "C" void kernel_launch(void* const* d_in, const int* in_sizes, int n_in,
                              void* d_out, int out_size, void* d_ws, size_t ws_size,
                              hipStream_t stream) {
    const float* feats = (const float*)d_in[0];
    const float* trans = (const float*)d_in[1];
    const int* mask = (const int*)d_in[2];
    const int* tags = (const int*)d_in[3];
    float* out = (float*)d_out;
    float* ws = (float*)d_ws;  // kB * kWS floats = 73.7 KB

    (void)hipMemsetAsync(out, 0, sizeof(float), stream);
    crf_scan_kernel<<<dim3(2 * kB), dim3(64), 0, stream>>>(feats, trans, mask, ws);
    crf_meet_kernel<<<dim3(kB), dim3(64), 0, stream>>>(feats, trans, mask, tags, ws, out);
}